// Round 10
// baseline (30.860 us; speedup 1.0000x reference)
//
#include <hip/hip_runtime.h>
#include <cstdint>

#define TPB 128   // 2 waves/block, each wave fully independent (no barriers)
#define LOG2E 1.4426950408889634f
#define LN2   0.69314718055994531f
#define RSTR  33                        // LDS row stride in u32 (32 + 1 pad)
#define VALID_LIM (1024u << 16)         // packed < this <=> element valid

// pack one element: (key11 << 16) | bf16(e),  e = 2^(s*log2e) unshifted
// (|s| <~ 5.5 -> e in [2^-8, 2^8]; all downstream f32 products range-safe;
//  numerics validated in R5 which passed with this exact packing)
__device__ __forceinline__ unsigned pack1(float s, int q, int r, int j)
{
    const float e = __builtin_amdgcn_exp2f(s * LOG2E);
    const unsigned b = __builtin_bit_cast(unsigned, e);
    const unsigned b16 = (b + 0x7FFFu + ((b >> 16) & 1u)) >> 16;   // RNE -> bf16
    return ((unsigned)((q << 10) + (r << 5) + j) << 16) | b16;
}

__global__ __launch_bounds__(TPB)
void pl_main(const float* __restrict__ scores,
             const int* __restrict__ ranks,
             const int* __restrict__ mask,
             float2* __restrict__ partials,
             int B)
{
    const int tid  = threadIdx.x;
    const int lane = tid & 63;
    const int wid  = tid >> 6;

    // wave-private packed tile: pw[r*33 + j]; stride 33 makes both the
    // write pattern (2 lanes/bank) and read pattern (2 lanes/bank) free.
    __shared__ unsigned pb[TPB / 64][64 * RSTR];   // 16.9 KB
    unsigned* pw = pb[wid];

    const int    rowBase = blockIdx.x * TPB + wid * 64;  // wave's first row
    const size_t base4   = (size_t)rowBase * 8;          // float4 index
    const size_t tot4    = (size_t)B * 8;

    const float4* sp = reinterpret_cast<const float4*>(scores) + base4;
    const int4*   rp = reinterpret_cast<const int4*>(ranks)   + base4;
    const int4*   mp = reinterpret_cast<const int4*>(mask)    + base4;

    // ---- coalesced load + pack + wave-private LDS write (NO barrier).
    // iter i: 64 lanes cover 8 complete rows; each lane holds row f>>3,
    // slots 4*(f&7)..+3.
    const bool full = (base4 + 8 * 64 <= tot4);          // uniform per wave
    #pragma unroll
    for (int i = 0; i < 8; ++i) {
        const int f = i * 64 + lane;
        if (full || base4 + f < tot4) {
            const float4 sv = sp[f];
            const int4   rv = rp[f];
            const int4   qv = mp[f];
            const int r  = f >> 3;          // local row 0..63
            const int j0 = (f & 7) << 2;    // slot base
            pw[r * RSTR + j0 + 0] = pack1(sv.x, qv.x, rv.x, j0 + 0);
            pw[r * RSTR + j0 + 1] = pack1(sv.y, qv.y, rv.y, j0 + 1);
            pw[r * RSTR + j0 + 2] = pack1(sv.z, qv.z, rv.z, j0 + 2);
            pw[r * RSTR + j0 + 3] = pack1(sv.w, qv.w, rv.w, j0 + 3);
        }
    }
    // wave-private region: compiler's lgkmcnt wait orders write->read; after
    // the wait, all 64 lanes' writes are visible wave-wide. No __syncthreads.

    float per_row = 0.0f, cnt = 0.0f;
    const int row = rowBase + lane;

    if (row < B) {
        // ---- read own row: single base address, immediate offsets
        unsigned U[32];
        #pragma unroll
        for (int j = 0; j < 32; ++j)
            U[j] = pw[lane * RSTR + j];

        // ---- payload-carrying bitonic sort (keys unique in high bits);
        // fully unrolled -> 2 VALU (v_min_u32/v_max_u32) per comparator
        #pragma unroll
        for (int kk = 2; kk <= 32; kk <<= 1) {
            #pragma unroll
            for (int jj = kk >> 1; jj > 0; jj >>= 1) {
                #pragma unroll
                for (int i = 0; i < 32; ++i) {
                    const int l = i ^ jj;
                    if (l > i) {
                        const unsigned a = U[i], b = U[l];
                        const unsigned mn = a < b ? a : b;
                        const unsigned mh = a < b ? b : a;
                        if ((i & kk) == 0) { U[i] = mn; U[l] = mh; }
                        else               { U[i] = mh; U[l] = mn; }
                    }
                }
            }
        }

        // ---- suffix sums + grouped product logs:
        // loss = ln2 * sum_{p<n} (log2 T_p - log2 e_p), T_p = suffix sum
        int   n = 0;
        float t = 0.0f, lsum = 0.0f;
        #pragma unroll
        for (int g = 7; g >= 0; --g) {
            float pT = 1.0f, pE = 1.0f;
            #pragma unroll
            for (int q = 3; q >= 0; --q) {
                const int p = 4*g + q;
                const bool v = (U[p] < VALID_LIM);
                const float e = __builtin_bit_cast(float, U[p] << 16);  // bf16->f32
                n  += v ? 1 : 0;
                t  += v ? e : 0.0f;
                pT *= v ? t : 1.0f;
                pE *= v ? e : 1.0f;
            }
            lsum += __builtin_amdgcn_logf(pT) - __builtin_amdgcn_logf(pE);  // hw log2
        }

        if (n >= 2) {
            per_row = (LN2 * lsum) / (float)n;
            cnt = 1.0f;
        }
    }

    // ---- wave-level reduction; one partial per wave, no cross-wave traffic
    #pragma unroll
    for (int d = 32; d >= 1; d >>= 1) {
        per_row += __shfl_xor(per_row, d, 64);
        cnt     += __shfl_xor(cnt,     d, 64);
    }
    if (lane == 0)
        partials[blockIdx.x * (TPB / 64) + wid] = make_float2(per_row, cnt);
}

__global__ __launch_bounds__(256)
void pl_final(const float2* __restrict__ partials, int np, float* __restrict__ out)
{
    const int tid = threadIdx.x;
    float s = 0.0f, c = 0.0f;
    for (int i = tid; i < np; i += 256) {
        const float2 v = partials[i];
        s += v.x;
        c += v.y;
    }
    #pragma unroll
    for (int d = 32; d >= 1; d >>= 1) {
        s += __shfl_xor(s, d, 64);
        c += __shfl_xor(c, d, 64);
    }
    __shared__ float sb[8];
    if ((tid & 63) == 0) {
        sb[tid >> 6]       = s;
        sb[4 + (tid >> 6)] = c;
    }
    __syncthreads();
    if (tid == 0) {
        const float S = (sb[0] + sb[1]) + (sb[2] + sb[3]);
        const float C = (sb[4] + sb[5]) + (sb[6] + sb[7]);
        out[0] = S / fmaxf(C, 1.0f);
    }
}

extern "C" void kernel_launch(void* const* d_in, const int* in_sizes, int n_in,
                              void* d_out, int out_size, void* d_ws, size_t ws_size,
                              hipStream_t stream)
{
    const float* scores = (const float*)d_in[0];
    const int*   ranks  = (const int*)d_in[1];
    const int*   mask   = (const int*)d_in[2];

    const int B  = in_sizes[0] / 32;
    const int nb = (B + TPB - 1) / TPB;
    const int np = nb * (TPB / 64);            // partials: one per wave

    float2* partials = (float2*)d_ws;          // np float2 (32 KB)

    pl_main<<<nb, TPB, 0, stream>>>(scores, ranks, mask, partials, B);
    pl_final<<<1, 256, 0, stream>>>(partials, np, (float*)d_out);
}